// Round 2
// baseline (418.369 us; speedup 1.0000x reference)
//
#include <hip/hip_runtime.h>
#include <hip/hip_bf16.h>
#include <cmath>

#define N_NODES 8192
#define NFEAT 512
#define NHID 512
#define NCLASS 64
#define NLAYERS 8
#define CAP 96

typedef __attribute__((ext_vector_type(8))) short bf16x8;
typedef __attribute__((ext_vector_type(4))) float f32x4;
typedef unsigned short u16;

__device__ inline float bf2f(short u) {
  union { unsigned int i; float f; } x;
  x.i = ((unsigned int)(u16)u) << 16;
  return x.f;
}
__device__ inline short f2bf(float f) {
  union { float f; unsigned int i; } x;
  x.f = f;
  unsigned int r = x.i + 0x7FFFu + ((x.i >> 16) & 1u);
  return (short)(r >> 16);
}

// ---------------- adjacency extraction: one streaming pass over adj ----------
__global__ __launch_bounds__(256)
void extract_kernel(const float* __restrict__ adj, int* __restrict__ idx,
                    int* __restrict__ cnt, int* __restrict__ colcnt)
{
  __shared__ int s_cnt;
  const int i = blockIdx.x;
  if (threadIdx.x == 0) s_cnt = 0;
  __syncthreads();
  const uint4* row = (const uint4*)(adj + (size_t)i * N_NODES);
  for (int c = threadIdx.x; c < N_NODES / 4; c += 256) {
    uint4 v = row[c];
    if ((v.x | v.y | v.z | v.w) == 0u) continue;  // 0.0f bit pattern is 0
    unsigned int vals[4] = {v.x, v.y, v.z, v.w};
    #pragma unroll
    for (int e = 0; e < 4; ++e) {
      if (vals[e] != 0u) {
        int p = atomicAdd(&s_cnt, 1);
        if (p < CAP) idx[(size_t)i * CAP + p] = c * 4 + e;
        atomicAdd(&colcnt[c * 4 + e], 1);
      }
    }
  }
  __syncthreads();
  if (threadIdx.x == 0) cnt[i] = min(s_cnt, CAP);
}

__global__ __launch_bounds__(256)
void dinv_kernel(const int* __restrict__ colcnt, float* __restrict__ dinv)
{
  int j = blockIdx.x * 256 + threadIdx.x;
  if (j < N_NODES) dinv[j] = 1.0f / sqrtf((float)colcnt[j] + 1.0f); // +1 for identity
}

// ---------------- f32 -> bf16 cast (x) ---------------------------------------
__global__ __launch_bounds__(256)
void cvt_bf16_kernel(const float* __restrict__ src, u16* __restrict__ dst, int n4)
{
  int i = blockIdx.x * 256 + threadIdx.x;
  if (i >= n4) return;
  float4 v = ((const float4*)src)[i];
  ushort4 o;
  o.x = (u16)f2bf(v.x); o.y = (u16)f2bf(v.y);
  o.z = (u16)f2bf(v.z); o.w = (u16)f2bf(v.w);
  ((ushort4*)dst)[i] = o;
}

// ---------------- weight transpose + cast: Wt[n][k] = W[k][n] ---------------
__global__ __launch_bounds__(256)
void transpose_cast_kernel(const float* __restrict__ fc1W, const float* __restrict__ convW,
                           u16* __restrict__ Wt)
{
  __shared__ float tile[32][33];
  const int m = blockIdx.z;
  const float* src = (m == 0) ? fc1W : convW + (size_t)(m - 1) * NHID * NHID;
  u16* dst = Wt + (size_t)m * NHID * NHID;
  const int k0 = blockIdx.x * 32, n0 = blockIdx.y * 32;
  const int tx = threadIdx.x & 31, ty = threadIdx.x >> 5; // 32 x 8
  #pragma unroll
  for (int r = 0; r < 32; r += 8)
    tile[ty + r][tx] = src[(size_t)(k0 + ty + r) * NHID + n0 + tx];
  __syncthreads();
  #pragma unroll
  for (int r = 0; r < 32; r += 8)
    dst[(size_t)(n0 + ty + r) * NHID + k0 + tx] = (u16)f2bf(tile[tx][ty + r]);
}

// ---------------- fc1 MFMA GEMM: H0 = bf16(relu(x @ W + b)) -----------------
#define AS1 __attribute__((address_space(1)))
#define AS3 __attribute__((address_space(3)))

__device__ inline void load16(const void* g, void* l) {
  __builtin_amdgcn_global_load_lds((const AS1 void*)g, (AS3 void*)l, 16, 0, 0);
}

__global__ __launch_bounds__(256, 2)
void fc1_gemm_kernel(const u16* __restrict__ A, const u16* __restrict__ Bt,
                     const float* __restrict__ bias, u16* __restrict__ outB)
{
  constexpr int K = 512, N = 512;
  __shared__ u16 ldsA[128 * 32];
  __shared__ u16 ldsB[128 * 32];
  const int tid = threadIdx.x;
  const int wave = tid >> 6, lane = tid & 63;
  const int m0 = blockIdx.x * 128, n0 = blockIdx.y * 128;
  const int wr = wave >> 1, wc = wave & 1;
  const int lrow = lane & 15, lk = lane >> 4;

  f32x4 acc[4][4];
  #pragma unroll
  for (int a = 0; a < 4; ++a)
    #pragma unroll
    for (int b = 0; b < 4; ++b)
      acc[a][b] = (f32x4){0.f, 0.f, 0.f, 0.f};

  for (int ks = 0; ks < K; ks += 32) {
    #pragma unroll
    for (int r = 0; r < 2; ++r) {
      const int g = r * 256 + wave * 64 + lane;     // 16B chunk id
      const int row = g >> 2, cc = g & 3;
      load16(A  + (size_t)(m0 + row) * K + ks + cc * 8, &ldsA[(size_t)(r * 256 + wave * 64) * 8]);
      load16(Bt + (size_t)(n0 + row) * K + ks + cc * 8, &ldsB[(size_t)(r * 256 + wave * 64) * 8]);
    }
    __syncthreads();
    bf16x8 af[4], bfr[4];
    #pragma unroll
    for (int mi = 0; mi < 4; ++mi)
      af[mi] = *(const bf16x8*)&ldsA[(wr * 64 + mi * 16 + lrow) * 32 + lk * 8];
    #pragma unroll
    for (int ni = 0; ni < 4; ++ni)
      bfr[ni] = *(const bf16x8*)&ldsB[(wc * 64 + ni * 16 + lrow) * 32 + lk * 8];
    #pragma unroll
    for (int mi = 0; mi < 4; ++mi)
      #pragma unroll
      for (int ni = 0; ni < 4; ++ni)
        acc[mi][ni] = __builtin_amdgcn_mfma_f32_16x16x32_bf16(af[mi], bfr[ni], acc[mi][ni], 0, 0, 0);
    __syncthreads();
  }

  #pragma unroll
  for (int mi = 0; mi < 4; ++mi) {
    #pragma unroll
    for (int ni = 0; ni < 4; ++ni) {
      #pragma unroll
      for (int r = 0; r < 4; ++r) {
        const int row = m0 + wr * 64 + mi * 16 + lk * 4 + r;
        const int col = n0 + wc * 64 + ni * 16 + lrow;
        float v = acc[mi][ni][r] + bias[col];
        outB[(size_t)row * N + col] = (u16)f2bf(fmaxf(v, 0.f));
      }
    }
  }
}

// ---------------- fused GCNII layer ------------------------------------------
// Per block: 32 output rows. Phase 1: IR = 0.9*(P@H) + 0.1*H0 into LDS (bf16,
// XOR-swizzled). Phase 2: Hout = relu(cA*IR + cB*(IR@W)), B-frags read straight
// from global (W is L2/L3-resident), skip term re-read from the LDS IR tile.
__device__ inline int swz(int row, int colByte) {
  return (row * 1024 + colByte) ^ ((row & 7) << 4);
}

__global__ __launch_bounds__(512, 2)
void layer_kernel(const u16* __restrict__ H, const u16* __restrict__ H0,
                  const float* __restrict__ dinv, const int* __restrict__ idx,
                  const int* __restrict__ cnt, const u16* __restrict__ W,
                  float cA, float cB, u16* __restrict__ outH)
{
  __shared__ u16 ldsA[32 * 512];      // 32 KB IR tile
  const int tid = threadIdx.x;
  const int wave = tid >> 6, lane = tid & 63;
  const int m0 = blockIdx.x * 32;
  char* ldsAb = (char*)ldsA;

  // ---- Phase 1: each wave computes 4 rows of IR, full 512 cols ----
  const int c0 = lane * 8;
  #pragma unroll
  for (int rr = 0; rr < 4; ++rr) {
    const int i = m0 + wave * 4 + rr;
    const int n = cnt[i];
    const int* nb = idx + (size_t)i * CAP;
    float acc[8];
    #pragma unroll
    for (int e = 0; e < 8; ++e) acc[e] = 0.f;
    int t = 0;
    for (; t + 4 <= n; t += 4) {                  // 4 gathers in flight
      const int j0 = nb[t], j1 = nb[t + 1], j2 = nb[t + 2], j3 = nb[t + 3];
      const float w0 = dinv[j0], w1 = dinv[j1], w2 = dinv[j2], w3 = dinv[j3];
      bf16x8 v0 = *(const bf16x8*)&H[(size_t)j0 * NHID + c0];
      bf16x8 v1 = *(const bf16x8*)&H[(size_t)j1 * NHID + c0];
      bf16x8 v2 = *(const bf16x8*)&H[(size_t)j2 * NHID + c0];
      bf16x8 v3 = *(const bf16x8*)&H[(size_t)j3 * NHID + c0];
      #pragma unroll
      for (int e = 0; e < 8; ++e) {
        acc[e] += w0 * bf2f(v0[e]);
        acc[e] += w1 * bf2f(v1[e]);
        acc[e] += w2 * bf2f(v2[e]);
        acc[e] += w3 * bf2f(v3[e]);
      }
    }
    for (; t < n; ++t) {
      const int j = nb[t];
      const float w = dinv[j];
      bf16x8 hv = *(const bf16x8*)&H[(size_t)j * NHID + c0];
      #pragma unroll
      for (int e = 0; e < 8; ++e) acc[e] += w * bf2f(hv[e]);
    }
    const float di = dinv[i];
    bf16x8 hr = *(const bf16x8*)&H[(size_t)i * NHID + c0];
    bf16x8 h0 = *(const bf16x8*)&H0[(size_t)i * NHID + c0];
    bf16x8 ov;
    #pragma unroll
    for (int e = 0; e < 8; ++e) {
      float v = 0.9f * di * (acc[e] + di * bf2f(hr[e])) + 0.1f * bf2f(h0[e]);
      ov[e] = f2bf(v);
    }
    *(bf16x8*)(ldsAb + swz(wave * 4 + rr, c0 * 2)) = ov;
  }
  __syncthreads();

  // ---- Phase 2: wave owns 64 output cols; MFMA over K=512, no barriers ----
  const int lrow = lane & 15, lk = lane >> 4;
  const int nbase = wave * 64;
  f32x4 acc2[2][4];
  #pragma unroll
  for (int a = 0; a < 2; ++a)
    #pragma unroll
    for (int b = 0; b < 4; ++b)
      acc2[a][b] = (f32x4){0.f, 0.f, 0.f, 0.f};

  #pragma unroll 2
  for (int kk = 0; kk < 16; ++kk) {
    bf16x8 a0 = *(const bf16x8*)(ldsAb + swz(lrow,      kk * 64 + lk * 16));
    bf16x8 a1 = *(const bf16x8*)(ldsAb + swz(16 + lrow, kk * 64 + lk * 16));
    bf16x8 bfr[4];
    #pragma unroll
    for (int ni = 0; ni < 4; ++ni)
      bfr[ni] = *(const bf16x8*)&W[(size_t)(nbase + ni * 16 + lrow) * NHID + kk * 32 + lk * 8];
    #pragma unroll
    for (int ni = 0; ni < 4; ++ni) {
      acc2[0][ni] = __builtin_amdgcn_mfma_f32_16x16x32_bf16(a0, bfr[ni], acc2[0][ni], 0, 0, 0);
      acc2[1][ni] = __builtin_amdgcn_mfma_f32_16x16x32_bf16(a1, bfr[ni], acc2[1][ni], 0, 0, 0);
    }
  }

  // ---- Epilogue: Hout = relu(cA*IR + cB*acc), IR re-read from LDS ----
  #pragma unroll
  for (int mi = 0; mi < 2; ++mi) {
    #pragma unroll
    for (int ni = 0; ni < 4; ++ni) {
      #pragma unroll
      for (int r = 0; r < 4; ++r) {
        const int row = mi * 16 + lk * 4 + r;
        const int col = nbase + ni * 16 + lrow;
        const u16 sraw = *(const u16*)(ldsAb + swz(row, col * 2));
        float v = cA * bf2f((short)sraw) + cB * acc2[mi][ni][r];
        outH[(size_t)(m0 + row) * NHID + col] = (u16)f2bf(fmaxf(v, 0.f));
      }
    }
  }
}

// ---------------- fc2 + -log_softmax fused ----------------------------------
__global__ __launch_bounds__(256)
void fc2_softmax_kernel(const u16* __restrict__ H, const float* __restrict__ W,
                        const float* __restrict__ b, float* __restrict__ out)
{
  __shared__ float sh[4][4][512];
  const int wave = threadIdx.x >> 6, lane = threadIdx.x & 63;
  const int rowBase = blockIdx.x * 16 + wave * 4;
  #pragma unroll
  for (int rr = 0; rr < 4; ++rr) {
    bf16x8 hv = *(const bf16x8*)&H[(size_t)(rowBase + rr) * NHID + lane * 8];
    #pragma unroll
    for (int e = 0; e < 8; ++e) sh[wave][rr][lane * 8 + e] = bf2f(hv[e]);
  }
  __syncthreads();
  const float bb = b[lane];
  float a0 = bb, a1 = bb, a2 = bb, a3 = bb;
  #pragma unroll 8
  for (int k = 0; k < 512; ++k) {
    const float w = W[k * 64 + lane];
    a0 += sh[wave][0][k] * w;
    a1 += sh[wave][1][k] * w;
    a2 += sh[wave][2][k] * w;
    a3 += sh[wave][3][k] * w;
  }
  float accs[4] = {a0, a1, a2, a3};
  #pragma unroll
  for (int rr = 0; rr < 4; ++rr) {
    const float v = accs[rr];
    float mx = v;
    for (int off = 32; off > 0; off >>= 1) mx = fmaxf(mx, __shfl_xor(mx, off));
    float s = __expf(v - mx);
    for (int off = 32; off > 0; off >>= 1) s += __shfl_xor(s, off);
    out[(size_t)(rowBase + rr) * NCLASS + lane] = -(v - mx - logf(s));
  }
}

// ---------------- launch -----------------------------------------------------
extern "C" void kernel_launch(void* const* d_in, const int* in_sizes, int n_in,
                              void* d_out, int out_size, void* d_ws, size_t ws_size,
                              hipStream_t stream)
{
  const float* x     = (const float*)d_in[0];
  const float* adj   = (const float*)d_in[1];
  const float* fc1W  = (const float*)d_in[2];
  const float* fc1b  = (const float*)d_in[3];
  const float* convW = (const float*)d_in[4];
  const float* fc2W  = (const float*)d_in[5];
  const float* fc2b  = (const float*)d_in[6];
  float* out = (float*)d_out;

  char* ws = (char*)d_ws;
  size_t off = 0;
  auto alloc = [&](size_t bytes) -> void* {
    void* p = ws + off;
    off = (off + bytes + 255) & ~(size_t)255;
    return p;
  };
  u16*   xb   = (u16*)alloc((size_t)N_NODES * NFEAT * 2);
  u16*   Wt   = (u16*)alloc((size_t)9 * NHID * NHID * 2);
  u16*   H0   = (u16*)alloc((size_t)N_NODES * NHID * 2);
  u16*   Ha   = (u16*)alloc((size_t)N_NODES * NHID * 2);
  u16*   Hb   = (u16*)alloc((size_t)N_NODES * NHID * 2);
  int*   idx  = (int*)alloc((size_t)N_NODES * CAP * 4);
  int*   cnt  = (int*)alloc((size_t)N_NODES * 4);
  int*   colc = (int*)alloc((size_t)N_NODES * 4);
  float* dinv = (float*)alloc((size_t)N_NODES * 4);

  hipMemsetAsync(colc, 0, N_NODES * 4, stream);
  extract_kernel<<<N_NODES, 256, 0, stream>>>(adj, idx, cnt, colc);
  dinv_kernel<<<N_NODES / 256, 256, 0, stream>>>(colc, dinv);
  cvt_bf16_kernel<<<(N_NODES * NFEAT / 4) / 256, 256, 0, stream>>>(x, xb, N_NODES * NFEAT / 4);
  transpose_cast_kernel<<<dim3(16, 16, 9), 256, 0, stream>>>(fc1W, convW, Wt);

  // fc1: H0 = bf16(relu(x @ fc1_W + b))
  fc1_gemm_kernel<<<dim3(64, 4), 256, 0, stream>>>(xb, Wt, fc1b, H0);

  const u16* Hin = H0;
  u16* bufs[2] = {Ha, Hb};
  for (int i = 0; i < NLAYERS; ++i) {
    const double beta = log(0.5 / (double)(i + 1) + 1.0);
    u16* Hout = bufs[i & 1];
    layer_kernel<<<N_NODES / 32, 512, 0, stream>>>(
        Hin, H0, dinv, idx, cnt, Wt + (size_t)(i + 1) * NHID * NHID,
        (float)(1.0 - beta), (float)beta, Hout);
    Hin = Hout;
  }

  fc2_softmax_kernel<<<N_NODES / 16, 256, 0, stream>>>(Hin, fc2W, fc2b, out);
}

// Round 3
// 361.768 us; speedup vs baseline: 1.1565x; 1.1565x over previous
//
#include <hip/hip_runtime.h>
#include <hip/hip_bf16.h>
#include <cmath>

#define N_NODES 8192
#define NFEAT 512
#define NHID 512
#define NCLASS 64
#define NLAYERS 8
#define CAP 96

typedef __attribute__((ext_vector_type(8))) short bf16x8;
typedef __attribute__((ext_vector_type(4))) float f32x4;
typedef unsigned short u16;

__device__ inline float bf2f(short u) {
  union { unsigned int i; float f; } x;
  x.i = ((unsigned int)(u16)u) << 16;
  return x.f;
}
__device__ inline short f2bf(float f) {
  union { float f; unsigned int i; } x;
  x.f = f;
  unsigned int r = x.i + 0x7FFFu + ((x.i >> 16) & 1u);
  return (short)(r >> 16);
}

// ---------------- adjacency extraction: one streaming pass over adj ----------
__global__ __launch_bounds__(256)
void extract_kernel(const float* __restrict__ adj, int* __restrict__ idx,
                    int* __restrict__ cnt, int* __restrict__ colcnt)
{
  __shared__ int s_cnt;
  const int i = blockIdx.x;
  if (threadIdx.x == 0) s_cnt = 0;
  __syncthreads();
  const uint4* row = (const uint4*)(adj + (size_t)i * N_NODES);
  for (int c = threadIdx.x; c < N_NODES / 4; c += 256) {
    uint4 v = row[c];
    if ((v.x | v.y | v.z | v.w) == 0u) continue;  // 0.0f bit pattern is 0
    unsigned int vals[4] = {v.x, v.y, v.z, v.w};
    #pragma unroll
    for (int e = 0; e < 4; ++e) {
      if (vals[e] != 0u) {
        int p = atomicAdd(&s_cnt, 1);
        if (p < CAP) idx[(size_t)i * CAP + p] = c * 4 + e;
        atomicAdd(&colcnt[c * 4 + e], 1);
      }
    }
  }
  __syncthreads();
  if (threadIdx.x == 0) cnt[i] = min(s_cnt, CAP);
}

__global__ __launch_bounds__(256)
void dinv_kernel(const int* __restrict__ colcnt, float* __restrict__ dinv)
{
  int j = blockIdx.x * 256 + threadIdx.x;
  if (j < N_NODES) dinv[j] = 1.0f / sqrtf((float)colcnt[j] + 1.0f); // +1 for identity
}

// ---------------- f32 -> bf16 cast (x) ---------------------------------------
__global__ __launch_bounds__(256)
void cvt_bf16_kernel(const float* __restrict__ src, u16* __restrict__ dst, int n4)
{
  int i = blockIdx.x * 256 + threadIdx.x;
  if (i >= n4) return;
  float4 v = ((const float4*)src)[i];
  ushort4 o;
  o.x = (u16)f2bf(v.x); o.y = (u16)f2bf(v.y);
  o.z = (u16)f2bf(v.z); o.w = (u16)f2bf(v.w);
  ((ushort4*)dst)[i] = o;
}

// ---------------- weight transpose + cast: Wt[n][k] = W[k][n] ---------------
__global__ __launch_bounds__(256)
void transpose_cast_kernel(const float* __restrict__ fc1W, const float* __restrict__ convW,
                           u16* __restrict__ Wt)
{
  __shared__ float tile[32][33];
  const int m = blockIdx.z;
  const float* src = (m == 0) ? fc1W : convW + (size_t)(m - 1) * NHID * NHID;
  u16* dst = Wt + (size_t)m * NHID * NHID;
  const int k0 = blockIdx.x * 32, n0 = blockIdx.y * 32;
  const int tx = threadIdx.x & 31, ty = threadIdx.x >> 5; // 32 x 8
  #pragma unroll
  for (int r = 0; r < 32; r += 8)
    tile[ty + r][tx] = src[(size_t)(k0 + ty + r) * NHID + n0 + tx];
  __syncthreads();
  #pragma unroll
  for (int r = 0; r < 32; r += 8)
    dst[(size_t)(n0 + ty + r) * NHID + k0 + tx] = (u16)f2bf(tile[tx][ty + r]);
}

// ---------------- MFMA GEMM, 64x128 tile, BK=32, double-buffered prefetch ---
#define AS1 __attribute__((address_space(1)))
#define AS3 __attribute__((address_space(3)))

__device__ inline void load16(const void* g, void* l) {
  __builtin_amdgcn_global_load_lds((const AS1 void*)g, (AS3 void*)l, 16, 0, 0);
}

// MODE 0: v=relu(acc+bias); out0=H0(bf16), out1=Hs=dinv*v
// MODE 1: v=relu(cA*skip + cB*acc); out0=Hs=dinv*v
// MODE 2: v=relu(cA*skip + cB*acc); out0=H (unscaled)
template<int MODE>
__global__ __launch_bounds__(256, 2)
void gemm_kernel(const u16* __restrict__ A, const u16* __restrict__ Bt,
                 const float* __restrict__ bias, const u16* __restrict__ skip,
                 const float* __restrict__ dinv, float cA, float cB,
                 u16* __restrict__ out0, u16* __restrict__ out1)
{
  constexpr int K = 512, N = 512;
  __shared__ u16 ldsA[2][64 * 32];
  __shared__ u16 ldsB[2][128 * 32];
  const int tid = threadIdx.x;
  const int wave = tid >> 6, lane = tid & 63;
  const int m0 = blockIdx.x * 64, n0 = blockIdx.y * 128;
  const int wr = wave >> 1, wc = wave & 1;
  const int lrow = lane & 15, lk = lane >> 4;

  f32x4 acc[2][4];
  #pragma unroll
  for (int a = 0; a < 2; ++a)
    #pragma unroll
    for (int b = 0; b < 4; ++b)
      acc[a][b] = (f32x4){0.f, 0.f, 0.f, 0.f};

  auto stage = [&](int b, int ks) {
    {  // A tile: 64 rows x 32 k = 256 chunks of 16B, one per thread
      const int c = wave * 64 + lane;
      load16(A + (size_t)(m0 + (c >> 2)) * K + ks + (c & 3) * 8,
             &ldsA[b][(wave * 64) * 8]);
    }
    #pragma unroll
    for (int r = 0; r < 2; ++r) {  // B tile: 128 rows x 32 k = 512 chunks
      const int c = r * 256 + wave * 64 + lane;
      load16(Bt + (size_t)(n0 + (c >> 2)) * K + ks + (c & 3) * 8,
             &ldsB[b][(r * 256 + wave * 64) * 8]);
    }
  };

  stage(0, 0);
  __syncthreads();

  for (int t = 0; t < 16; ++t) {
    const int b = t & 1;
    if (t + 1 < 16) stage(b ^ 1, (t + 1) * 32);   // prefetch flies under MFMA
    bf16x8 af[2], bfr[4];
    #pragma unroll
    for (int mi = 0; mi < 2; ++mi)
      af[mi] = *(const bf16x8*)&ldsA[b][(wr * 32 + mi * 16 + lrow) * 32 + lk * 8];
    #pragma unroll
    for (int ni = 0; ni < 4; ++ni)
      bfr[ni] = *(const bf16x8*)&ldsB[b][(wc * 64 + ni * 16 + lrow) * 32 + lk * 8];
    #pragma unroll
    for (int mi = 0; mi < 2; ++mi)
      #pragma unroll
      for (int ni = 0; ni < 4; ++ni)
        acc[mi][ni] = __builtin_amdgcn_mfma_f32_16x16x32_bf16(af[mi], bfr[ni], acc[mi][ni], 0, 0, 0);
    __syncthreads();   // drains vmcnt (prefetch landed) + lgkm, swaps buffers
  }

  #pragma unroll
  for (int mi = 0; mi < 2; ++mi) {
    #pragma unroll
    for (int ni = 0; ni < 4; ++ni) {
      #pragma unroll
      for (int r = 0; r < 4; ++r) {
        const int row = m0 + wr * 32 + mi * 16 + lk * 4 + r;
        const int col = n0 + wc * 64 + ni * 16 + lrow;
        const size_t o = (size_t)row * N + col;
        float v = acc[mi][ni][r];
        if (MODE == 0) {
          v = fmaxf(v + bias[col], 0.f);
          out0[o] = (u16)f2bf(v);                    // H0 (unscaled)
          out1[o] = (u16)f2bf(dinv[row] * v);        // Hs (pre-scaled)
        } else {
          v = fmaxf(cA * bf2f((short)skip[o]) + cB * v, 0.f);
          out0[o] = (u16)f2bf(MODE == 1 ? dinv[row] * v : v);
        }
      }
    }
  }
}

// ---------------- SpMM: IR = 0.9*(P@H) + 0.1*H0, H pre-scaled ---------------
// wave per row; neighbor indices live in lane registers, broadcast by shfl.
__global__ __launch_bounds__(256)
void spmm_kernel(const u16* __restrict__ Hs, const u16* __restrict__ H0,
                 const float* __restrict__ dinv, const int* __restrict__ idx,
                 const int* __restrict__ cnt, u16* __restrict__ IR)
{
  const int wave = threadIdx.x >> 6, lane = threadIdx.x & 63;
  const int i = blockIdx.x * 4 + wave;
  const int c0 = lane * 8;
  const int n = cnt[i];
  int jreg = 0;
  if (lane < n) jreg = idx[(size_t)i * CAP + lane] & (N_NODES - 1);

  float acc[8];
  #pragma unroll
  for (int e = 0; e < 8; ++e) acc[e] = 0.f;

  const int nn = min(n, 64);
  int t = 0;
  for (; t + 8 <= nn; t += 8) {          // 8 gathers in flight
    bf16x8 v[8];
    #pragma unroll
    for (int u = 0; u < 8; ++u) {
      const int j = __shfl(jreg, t + u);
      v[u] = *(const bf16x8*)&Hs[(size_t)j * NHID + c0];
    }
    #pragma unroll
    for (int u = 0; u < 8; ++u)
      #pragma unroll
      for (int e = 0; e < 8; ++e)
        acc[e] += bf2f(v[u][e]);
  }
  for (; t < nn; ++t) {
    const int j = __shfl(jreg, t);
    bf16x8 v = *(const bf16x8*)&Hs[(size_t)j * NHID + c0];
    #pragma unroll
    for (int e = 0; e < 8; ++e) acc[e] += bf2f(v[e]);
  }
  for (; t < n; ++t) {                   // n > 64: essentially never
    const int j = idx[(size_t)i * CAP + t] & (N_NODES - 1);
    bf16x8 v = *(const bf16x8*)&Hs[(size_t)j * NHID + c0];
    #pragma unroll
    for (int e = 0; e < 8; ++e) acc[e] += bf2f(v[e]);
  }

  const float di = dinv[i];
  bf16x8 self = *(const bf16x8*)&Hs[(size_t)i * NHID + c0];
  bf16x8 h0   = *(const bf16x8*)&H0[(size_t)i * NHID + c0];
  bf16x8 ov;
  #pragma unroll
  for (int e = 0; e < 8; ++e) {
    float v = 0.9f * di * (acc[e] + bf2f(self[e])) + 0.1f * bf2f(h0[e]);
    ov[e] = f2bf(v);
  }
  *(bf16x8*)&IR[(size_t)i * NHID + c0] = ov;
}

// ---------------- fc2 + -log_softmax fused ----------------------------------
__global__ __launch_bounds__(256)
void fc2_softmax_kernel(const u16* __restrict__ H, const float* __restrict__ W,
                        const float* __restrict__ b, float* __restrict__ out)
{
  __shared__ float sh[4][4][512];
  const int wave = threadIdx.x >> 6, lane = threadIdx.x & 63;
  const int rowBase = blockIdx.x * 16 + wave * 4;
  #pragma unroll
  for (int rr = 0; rr < 4; ++rr) {
    bf16x8 hv = *(const bf16x8*)&H[(size_t)(rowBase + rr) * NHID + lane * 8];
    #pragma unroll
    for (int e = 0; e < 8; ++e) sh[wave][rr][lane * 8 + e] = bf2f(hv[e]);
  }
  __syncthreads();
  const float bb = b[lane];
  float a0 = bb, a1 = bb, a2 = bb, a3 = bb;
  #pragma unroll 8
  for (int k = 0; k < 512; ++k) {
    const float w = W[k * 64 + lane];
    a0 += sh[wave][0][k] * w;
    a1 += sh[wave][1][k] * w;
    a2 += sh[wave][2][k] * w;
    a3 += sh[wave][3][k] * w;
  }
  float accs[4] = {a0, a1, a2, a3};
  #pragma unroll
  for (int rr = 0; rr < 4; ++rr) {
    const float v = accs[rr];
    float mx = v;
    for (int off = 32; off > 0; off >>= 1) mx = fmaxf(mx, __shfl_xor(mx, off));
    float s = __expf(v - mx);
    for (int off = 32; off > 0; off >>= 1) s += __shfl_xor(s, off);
    out[(size_t)(rowBase + rr) * NCLASS + lane] = -(v - mx - logf(s));
  }
}

// ---------------- launch -----------------------------------------------------
extern "C" void kernel_launch(void* const* d_in, const int* in_sizes, int n_in,
                              void* d_out, int out_size, void* d_ws, size_t ws_size,
                              hipStream_t stream)
{
  const float* x     = (const float*)d_in[0];
  const float* adj   = (const float*)d_in[1];
  const float* fc1W  = (const float*)d_in[2];
  const float* fc1b  = (const float*)d_in[3];
  const float* convW = (const float*)d_in[4];
  const float* fc2W  = (const float*)d_in[5];
  const float* fc2b  = (const float*)d_in[6];
  float* out = (float*)d_out;

  char* ws = (char*)d_ws;
  size_t off = 0;
  auto alloc = [&](size_t bytes) -> void* {
    void* p = ws + off;
    off = (off + bytes + 255) & ~(size_t)255;
    return p;
  };
  u16*   xb   = (u16*)alloc((size_t)N_NODES * NFEAT * 2);
  u16*   Wt   = (u16*)alloc((size_t)9 * NHID * NHID * 2);
  u16*   H0   = (u16*)alloc((size_t)N_NODES * NHID * 2);
  u16*   HsA  = (u16*)alloc((size_t)N_NODES * NHID * 2);
  u16*   HsB  = (u16*)alloc((size_t)N_NODES * NHID * 2);
  u16*   IR   = (u16*)alloc((size_t)N_NODES * NHID * 2);
  int*   idx  = (int*)alloc((size_t)N_NODES * CAP * 4);
  int*   cnt  = (int*)alloc((size_t)N_NODES * 4);
  int*   colc = (int*)alloc((size_t)N_NODES * 4);
  float* dinv = (float*)alloc((size_t)N_NODES * 4);

  hipMemsetAsync(colc, 0, N_NODES * 4, stream);
  extract_kernel<<<N_NODES, 256, 0, stream>>>(adj, idx, cnt, colc);
  dinv_kernel<<<N_NODES / 256, 256, 0, stream>>>(colc, dinv);
  cvt_bf16_kernel<<<(N_NODES * NFEAT / 4) / 256, 256, 0, stream>>>(x, xb, N_NODES * NFEAT / 4);
  transpose_cast_kernel<<<dim3(16, 16, 9), 256, 0, stream>>>(fc1W, convW, Wt);

  // fc1: H0 = relu(x@W+b), Hs = dinv*H0
  gemm_kernel<0><<<dim3(128, 4), 256, 0, stream>>>(xb, Wt, fc1b, nullptr, dinv, 0.f, 0.f, H0, HsA);

  const u16* Hin = HsA;
  for (int i = 0; i < NLAYERS; ++i) {
    const double beta = log(0.5 / (double)(i + 1) + 1.0);
    const float cA = (float)(1.0 - beta), cB = (float)beta;
    spmm_kernel<<<N_NODES / 4, 256, 0, stream>>>(Hin, H0, dinv, idx, cnt, IR);
    u16* Hout = (Hin == HsA) ? HsB : HsA;
    if (i < NLAYERS - 1)
      gemm_kernel<1><<<dim3(128, 4), 256, 0, stream>>>(
          IR, Wt + (size_t)(i + 1) * NHID * NHID, nullptr, IR, dinv, cA, cB, Hout, nullptr);
    else
      gemm_kernel<2><<<dim3(128, 4), 256, 0, stream>>>(
          IR, Wt + (size_t)(i + 1) * NHID * NHID, nullptr, IR, dinv, cA, cB, Hout, nullptr);
    Hin = Hout;
  }

  fc2_softmax_kernel<<<N_NODES / 16, 256, 0, stream>>>((const u16*)Hin, fc2W, fc2b, out);
}

// Round 4
// 305.277 us; speedup vs baseline: 1.3705x; 1.1850x over previous
//
#include <hip/hip_runtime.h>
#include <hip/hip_bf16.h>
#include <cmath>

#define N_NODES 8192
#define NFEAT 512
#define NHID 512
#define NCLASS 64
#define NLAYERS 8
#define CAP 96

typedef __attribute__((ext_vector_type(8))) short bf16x8;
typedef __attribute__((ext_vector_type(4))) float f32x4;
typedef unsigned short u16;

__device__ inline float bf2f(short u) {
  union { unsigned int i; float f; } x;
  x.i = ((unsigned int)(u16)u) << 16;
  return x.f;
}
__device__ inline short f2bf(float f) {
  union { float f; unsigned int i; } x;
  x.f = f;
  unsigned int r = x.i + 0x7FFFu + ((x.i >> 16) & 1u);
  return (short)(r >> 16);
}

// ---------------- adjacency extraction: one streaming pass over adj ----------
__global__ __launch_bounds__(256)
void extract_kernel(const float* __restrict__ adj, int* __restrict__ idx,
                    int* __restrict__ cnt, int* __restrict__ colcnt)
{
  __shared__ int s_cnt;
  const int i = blockIdx.x;
  if (threadIdx.x == 0) s_cnt = 0;
  __syncthreads();
  const uint4* row = (const uint4*)(adj + (size_t)i * N_NODES);
  for (int c = threadIdx.x; c < N_NODES / 4; c += 256) {
    uint4 v = row[c];
    if ((v.x | v.y | v.z | v.w) == 0u) continue;  // 0.0f bit pattern is 0
    unsigned int vals[4] = {v.x, v.y, v.z, v.w};
    #pragma unroll
    for (int e = 0; e < 4; ++e) {
      if (vals[e] != 0u) {
        int p = atomicAdd(&s_cnt, 1);
        if (p < CAP) idx[(size_t)i * CAP + p] = c * 4 + e;
        atomicAdd(&colcnt[c * 4 + e], 1);
      }
    }
  }
  __syncthreads();
  if (threadIdx.x == 0) cnt[i] = min(s_cnt, CAP);
}

__global__ __launch_bounds__(256)
void dinv_kernel(const int* __restrict__ colcnt, float* __restrict__ dinv)
{
  int j = blockIdx.x * 256 + threadIdx.x;
  if (j < N_NODES) dinv[j] = 1.0f / sqrtf((float)colcnt[j] + 1.0f); // +1 for identity
}

// ---------------- f32 -> bf16 cast (x) ---------------------------------------
__global__ __launch_bounds__(256)
void cvt_bf16_kernel(const float* __restrict__ src, u16* __restrict__ dst, int n4)
{
  int i = blockIdx.x * 256 + threadIdx.x;
  if (i >= n4) return;
  float4 v = ((const float4*)src)[i];
  ushort4 o;
  o.x = (u16)f2bf(v.x); o.y = (u16)f2bf(v.y);
  o.z = (u16)f2bf(v.z); o.w = (u16)f2bf(v.w);
  ((ushort4*)dst)[i] = o;
}

// ---------------- weight transpose + cast -----------------------------------
// z=0:   Wt[0]  = fc1W^T                         (bf16, [512][512])
// z=1..8: Wt[z] = cB[z-1]*convW[z-1]^T + cA[z-1]*I  (the GCNII identity fold)
// z=9:   Wt2    = fc2W^T                          (bf16, [64][512])
struct Coefs { float cA[8]; float cB[8]; };

__global__ __launch_bounds__(256)
void transpose_cast_kernel(const float* __restrict__ fc1W, const float* __restrict__ convW,
                           const float* __restrict__ fc2W,
                           u16* __restrict__ Wt, u16* __restrict__ Wt2, Coefs co)
{
  __shared__ float tile[32][33];
  const int m = blockIdx.z;
  const int k0 = blockIdx.x * 32, n0 = blockIdx.y * 32;
  if (m == 9 && n0 >= 64) return;
  const int tx = threadIdx.x & 31, ty = threadIdx.x >> 5; // 32 x 8
  if (m == 9) {
    #pragma unroll
    for (int r = 0; r < 32; r += 8)
      tile[ty + r][tx] = fc2W[(size_t)(k0 + ty + r) * 64 + n0 + tx];
    __syncthreads();
    #pragma unroll
    for (int r = 0; r < 32; r += 8)
      Wt2[(size_t)(n0 + ty + r) * 512 + k0 + tx] = (u16)f2bf(tile[tx][ty + r]);
    return;
  }
  const float* src = (m == 0) ? fc1W : convW + (size_t)(m - 1) * NHID * NHID;
  u16* dst = Wt + (size_t)m * NHID * NHID;
  float cA = 0.f, cB = 1.f;
  if (m >= 1) { cA = co.cA[m - 1]; cB = co.cB[m - 1]; }
  #pragma unroll
  for (int r = 0; r < 32; r += 8)
    tile[ty + r][tx] = src[(size_t)(k0 + ty + r) * NHID + n0 + tx];
  __syncthreads();
  #pragma unroll
  for (int r = 0; r < 32; r += 8) {
    const int krow = k0 + tx, ncol = n0 + ty + r;
    float val = cB * tile[tx][ty + r];
    if (m >= 1 && krow == ncol) val += cA;
    dst[(size_t)ncol * NHID + krow] = (u16)f2bf(val);
  }
}

// ---------------- MFMA GEMM, 64x64 tile, BK=64, swizzled LDS, 4 blocks/CU ---
#define AS1 __attribute__((address_space(1)))
#define AS3 __attribute__((address_space(3)))

__device__ inline void load16(const void* g, void* l) {
  __builtin_amdgcn_global_load_lds((const AS1 void*)g, (AS3 void*)l, 16, 0, 0);
}

// MODE 0: v=relu(acc+bias); out0=H0(bf16), out1=Hs=dinv*v       [fc1]
// MODE 1: v=relu(acc);      out0=Hs=dinv*v                      [layers 0..6]
// MODE 2: v=relu(acc);      out0=H (unscaled)                   [layer 7]
// MODE 3: logits=acc+bias -> -log_softmax -> outF (f32)         [fc2, N=64]
template<int MODE>
__global__ __launch_bounds__(256, 4)
void gemm_kernel(const u16* __restrict__ A, const u16* __restrict__ Bt,
                 const float* __restrict__ bias, const float* __restrict__ dinv,
                 u16* __restrict__ out0, u16* __restrict__ out1,
                 float* __restrict__ outF)
{
  constexpr int K = 512;
  constexpr int N = (MODE == 3) ? NCLASS : 512;
  __shared__ u16 lds[2][2][64 * 64];   // [buf][A/B][tile]  32 KB total
  const int tid = threadIdx.x;
  const int wave = tid >> 6, lane = tid & 63;

  // chunked XCD swizzle: XCD k gets a contiguous logical range (same-A-panel
  // blocks share the XCD's L2)
  const int cpx = gridDim.x >> 3;
  const int logical = (blockIdx.x & 7) * cpx + (blockIdx.x >> 3);
  const int mblk = (MODE == 3) ? logical : (logical >> 3);
  const int nblk = (MODE == 3) ? 0 : (logical & 7);
  const int m0 = mblk * 64, n0 = nblk * 64;

  const int wr = wave >> 1, wc = wave & 1;
  const int lrow = lane & 15, lk = lane >> 4;

  f32x4 acc[2][2];
  #pragma unroll
  for (int a = 0; a < 2; ++a)
    #pragma unroll
    for (int b = 0; b < 2; ++b)
      acc[a][b] = (f32x4){0.f, 0.f, 0.f, 0.f};

  // stage one 64x64 tile pair; LDS dest linear, XOR-swizzle folded into the
  // per-lane GLOBAL source chunk (rule 21: both-sides-or-neither)
  auto stage = [&](int b, int ks) {
    #pragma unroll
    for (int r = 0; r < 2; ++r) {
      const int c = r * 256 + wave * 64 + lane;   // 512 chunks of 16B per tile
      const int row = c >> 3;                     // 8 chunks per 128B row
      const int sc = (c & 7) ^ (row & 7);         // swizzled source chunk
      load16(A  + (size_t)(m0 + row) * K + ks + sc * 8, &lds[b][0][(r * 256 + wave * 64) * 8]);
      load16(Bt + (size_t)(n0 + row) * K + ks + sc * 8, &lds[b][1][(r * 256 + wave * 64) * 8]);
    }
  };

  stage(0, 0);
  __syncthreads();

  for (int t = 0; t < 8; ++t) {
    const int b = t & 1;
    if (t + 1 < 8) stage(b ^ 1, (t + 1) * 64);    // prefetch under MFMA
    const char* pA = (const char*)lds[b][0];
    const char* pB = (const char*)lds[b][1];
    bf16x8 af[2][2], bfr[2][2];
    #pragma unroll
    for (int mi = 0; mi < 2; ++mi) {
      const int row = wr * 32 + mi * 16 + lrow;
      #pragma unroll
      for (int ks2 = 0; ks2 < 2; ++ks2) {
        const int j = ks2 * 4 + lk;               // logical 16B chunk in row
        af[mi][ks2] = *(const bf16x8*)(pA + row * 128 + ((j ^ (row & 7)) * 16));
      }
    }
    #pragma unroll
    for (int ni = 0; ni < 2; ++ni) {
      const int row = wc * 32 + ni * 16 + lrow;
      #pragma unroll
      for (int ks2 = 0; ks2 < 2; ++ks2) {
        const int j = ks2 * 4 + lk;
        bfr[ni][ks2] = *(const bf16x8*)(pB + row * 128 + ((j ^ (row & 7)) * 16));
      }
    }
    #pragma unroll
    for (int ks2 = 0; ks2 < 2; ++ks2)
      #pragma unroll
      for (int mi = 0; mi < 2; ++mi)
        #pragma unroll
        for (int ni = 0; ni < 2; ++ni)
          acc[mi][ni] = __builtin_amdgcn_mfma_f32_16x16x32_bf16(af[mi][ks2], bfr[ni][ks2], acc[mi][ni], 0, 0, 0);
    __syncthreads();
  }

  if (MODE != 3) {
    #pragma unroll
    for (int mi = 0; mi < 2; ++mi) {
      #pragma unroll
      for (int ni = 0; ni < 2; ++ni) {
        #pragma unroll
        for (int r = 0; r < 4; ++r) {
          const int row = m0 + wr * 32 + mi * 16 + lk * 4 + r;
          const int col = n0 + wc * 32 + ni * 16 + lrow;
          const size_t o = (size_t)row * N + col;
          float v = acc[mi][ni][r];
          if (MODE == 0) {
            v = fmaxf(v + bias[col], 0.f);
            out0[o] = (u16)f2bf(v);                 // H0
            out1[o] = (u16)f2bf(dinv[row] * v);     // Hs
          } else {
            v = fmaxf(v, 0.f);
            out0[o] = (u16)f2bf(MODE == 1 ? dinv[row] * v : v);
          }
        }
      }
    }
  } else {
    // stash logits (+bias) in LDS, then per-row softmax with lane = class
    float* Cf = (float*)&lds[0][0][0];              // 64x65 f32 = 16.6 KB
    #pragma unroll
    for (int mi = 0; mi < 2; ++mi)
      #pragma unroll
      for (int ni = 0; ni < 2; ++ni)
        #pragma unroll
        for (int r = 0; r < 4; ++r) {
          const int row = wr * 32 + mi * 16 + lk * 4 + r;
          const int col = wc * 32 + ni * 16 + lrow;
          Cf[row * 65 + col] = acc[mi][ni][r] + bias[col];
        }
    __syncthreads();
    #pragma unroll 4
    for (int r = 0; r < 16; ++r) {
      const int row = wave * 16 + r;
      const float v = Cf[row * 65 + lane];
      float mx = v;
      #pragma unroll
      for (int off = 32; off > 0; off >>= 1) mx = fmaxf(mx, __shfl_xor(mx, off));
      float s = __expf(v - mx);
      #pragma unroll
      for (int off = 32; off > 0; off >>= 1) s += __shfl_xor(s, off);
      outF[(size_t)(m0 + row) * NCLASS + lane] = -(v - mx - logf(s));
    }
  }
}

// ---------------- SpMM: IR = 0.9*(P@H) + 0.1*H0, H pre-scaled ---------------
__global__ __launch_bounds__(256)
void spmm_kernel(const u16* __restrict__ Hs, const u16* __restrict__ H0,
                 const float* __restrict__ dinv, const int* __restrict__ idx,
                 const int* __restrict__ cnt, u16* __restrict__ IR)
{
  const int wave = threadIdx.x >> 6, lane = threadIdx.x & 63;
  const int i = blockIdx.x * 4 + wave;
  const int c0 = lane * 8;
  const int n = cnt[i];
  int jreg = 0;
  if (lane < n) jreg = idx[(size_t)i * CAP + lane] & (N_NODES - 1);

  float acc[8];
  #pragma unroll
  for (int e = 0; e < 8; ++e) acc[e] = 0.f;

  const int nn = min(n, 64);
  int t = 0;
  for (; t + 8 <= nn; t += 8) {          // 8 gathers in flight
    bf16x8 v[8];
    #pragma unroll
    for (int u = 0; u < 8; ++u) {
      const int j = __shfl(jreg, t + u);
      v[u] = *(const bf16x8*)&Hs[(size_t)j * NHID + c0];
    }
    #pragma unroll
    for (int u = 0; u < 8; ++u)
      #pragma unroll
      for (int e = 0; e < 8; ++e)
        acc[e] += bf2f(v[u][e]);
  }
  for (; t < nn; ++t) {
    const int j = __shfl(jreg, t);
    bf16x8 v = *(const bf16x8*)&Hs[(size_t)j * NHID + c0];
    #pragma unroll
    for (int e = 0; e < 8; ++e) acc[e] += bf2f(v[e]);
  }
  for (; t < n; ++t) {                   // n > 64: essentially never
    const int j = idx[(size_t)i * CAP + t] & (N_NODES - 1);
    bf16x8 v = *(const bf16x8*)&Hs[(size_t)j * NHID + c0];
    #pragma unroll
    for (int e = 0; e < 8; ++e) acc[e] += bf2f(v[e]);
  }

  const float di = dinv[i];
  bf16x8 self = *(const bf16x8*)&Hs[(size_t)i * NHID + c0];
  bf16x8 h0   = *(const bf16x8*)&H0[(size_t)i * NHID + c0];
  bf16x8 ov;
  #pragma unroll
  for (int e = 0; e < 8; ++e) {
    float v = 0.9f * di * (acc[e] + bf2f(self[e])) + 0.1f * bf2f(h0[e]);
    ov[e] = f2bf(v);
  }
  *(bf16x8*)&IR[(size_t)i * NHID + c0] = ov;
}

// ---------------- launch -----------------------------------------------------
extern "C" void kernel_launch(void* const* d_in, const int* in_sizes, int n_in,
                              void* d_out, int out_size, void* d_ws, size_t ws_size,
                              hipStream_t stream)
{
  const float* x     = (const float*)d_in[0];
  const float* adj   = (const float*)d_in[1];
  const float* fc1W  = (const float*)d_in[2];
  const float* fc1b  = (const float*)d_in[3];
  const float* convW = (const float*)d_in[4];
  const float* fc2W  = (const float*)d_in[5];
  const float* fc2b  = (const float*)d_in[6];
  float* out = (float*)d_out;

  char* ws = (char*)d_ws;
  size_t off = 0;
  auto alloc = [&](size_t bytes) -> void* {
    void* p = ws + off;
    off = (off + bytes + 255) & ~(size_t)255;
    return p;
  };
  u16*   xb   = (u16*)alloc((size_t)N_NODES * NFEAT * 2);
  u16*   Wt   = (u16*)alloc((size_t)9 * NHID * NHID * 2);
  u16*   Wt2  = (u16*)alloc((size_t)NCLASS * NHID * 2);
  u16*   H0   = (u16*)alloc((size_t)N_NODES * NHID * 2);
  u16*   HsA  = (u16*)alloc((size_t)N_NODES * NHID * 2);
  u16*   HsB  = (u16*)alloc((size_t)N_NODES * NHID * 2);
  u16*   IR   = (u16*)alloc((size_t)N_NODES * NHID * 2);
  int*   idx  = (int*)alloc((size_t)N_NODES * CAP * 4);
  int*   cnt  = (int*)alloc((size_t)N_NODES * 4);
  int*   colc = (int*)alloc((size_t)N_NODES * 4);
  float* dinv = (float*)alloc((size_t)N_NODES * 4);

  Coefs co;
  for (int i = 0; i < NLAYERS; ++i) {
    const double beta = log(0.5 / (double)(i + 1) + 1.0);
    co.cA[i] = (float)(1.0 - beta);
    co.cB[i] = (float)beta;
  }

  hipMemsetAsync(colc, 0, N_NODES * 4, stream);
  extract_kernel<<<N_NODES, 256, 0, stream>>>(adj, idx, cnt, colc);
  dinv_kernel<<<N_NODES / 256, 256, 0, stream>>>(colc, dinv);
  cvt_bf16_kernel<<<(N_NODES * NFEAT / 4) / 256, 256, 0, stream>>>(x, xb, N_NODES * NFEAT / 4);
  transpose_cast_kernel<<<dim3(16, 16, 10), 256, 0, stream>>>(fc1W, convW, fc2W, Wt, Wt2, co);

  // fc1: H0 = relu(x@W+b), Hs = dinv*H0
  gemm_kernel<0><<<1024, 256, 0, stream>>>(xb, Wt, fc1b, dinv, H0, HsA, nullptr);

  const u16* Hin = HsA;
  for (int i = 0; i < NLAYERS; ++i) {
    spmm_kernel<<<N_NODES / 4, 256, 0, stream>>>(Hin, H0, dinv, idx, cnt, IR);
    u16* Hout = (Hin == HsA) ? HsB : HsA;
    if (i < NLAYERS - 1)
      gemm_kernel<1><<<1024, 256, 0, stream>>>(
          IR, Wt + (size_t)(i + 1) * NHID * NHID, nullptr, dinv, Hout, nullptr, nullptr);
    else
      gemm_kernel<2><<<1024, 256, 0, stream>>>(
          IR, Wt + (size_t)(i + 1) * NHID * NHID, nullptr, dinv, Hout, nullptr, nullptr);
    Hin = Hout;
  }

  // fc2 + -log_softmax (MFMA, N=64)
  gemm_kernel<3><<<128, 256, 0, stream>>>((const u16*)Hin, Wt2, fc2b, nullptr, nullptr, nullptr, out);
}